// Round 1
// baseline (630.657 us; speedup 1.0000x reference)
//
#include <hip/hip_runtime.h>
#include <math.h>

// NNFM loss on MI355X.
// loss = mean_i (1 - max_j (xhat_i . shat_j)),  xhat/shat = column-normalized feats.
// Pipeline: norms -> transpose+normalize+bf16 -> MFMA GEMM w/ fused row-max -> reduce.

#define C_DIM 768
#define P_DIM 16384
#define BM 128
#define BN 128
#define BK 64
#define KCH 12          // 768/64
#define JSPLIT 4
#define NJT 32          // (P/JSPLIT)/BN
#define EPSF 1e-8f

typedef __bf16 bf16;
typedef bf16 bf16x8 __attribute__((ext_vector_type(8)));
typedef float f32x4 __attribute__((ext_vector_type(4)));

// workspace layout (bytes)
#define OFF_XN   0
#define OFF_SN   25165824UL                 // 16384*768*2
#define OFF_INVX 50331648UL
#define OFF_INVS 50397184UL
#define OFF_MAX  50462720UL                 // 8 * 16384 * 4 = 524288 bytes

__device__ __forceinline__ void async_copy16(const void* gsrc, void* ldst) {
    __builtin_amdgcn_global_load_lds(
        (const __attribute__((address_space(1))) void*)gsrc,
        (__attribute__((address_space(3))) void*)ldst,
        16, 0, 0);
}

// --- 1. column L2 norms (inverse, +eps) for both inputs ---
__global__ void norm_kernel(const float* __restrict__ x, const float* __restrict__ s,
                            float* __restrict__ invx, float* __restrict__ invs) {
    const float4* src = (const float4*)(blockIdx.y == 0 ? x : s);
    float* dst = (blockIdx.y == 0) ? invx : invs;
    int j4 = blockIdx.x * 256 + threadIdx.x;       // 0..4095, each handles 4 columns
    float sx = 0.f, sy = 0.f, sz = 0.f, sw = 0.f;
    for (int c = 0; c < C_DIM; ++c) {
        float4 v = src[c * (P_DIM / 4) + j4];
        sx += v.x * v.x; sy += v.y * v.y; sz += v.z * v.z; sw += v.w * v.w;
    }
    int j = j4 * 4;
    dst[j + 0] = 1.0f / (sqrtf(sx) + EPSF);
    dst[j + 1] = 1.0f / (sqrtf(sy) + EPSF);
    dst[j + 2] = 1.0f / (sqrtf(sz) + EPSF);
    dst[j + 3] = 1.0f / (sqrtf(sw) + EPSF);
}

// --- 2. transpose [c][p] -> [p][c], normalize, cast bf16 ---
__global__ void tnorm_kernel(const float* __restrict__ x, const float* __restrict__ s,
                             const float* __restrict__ invx, const float* __restrict__ invs,
                             bf16* __restrict__ Xn, bf16* __restrict__ Sn) {
    __shared__ float tile[64][65];
    const float* src = blockIdx.z ? s : x;
    const float* inv = blockIdx.z ? invs : invx;
    bf16* dst = blockIdx.z ? Sn : Xn;
    int c0 = blockIdx.y * 64;
    int j0 = blockIdx.x * 64;
    int t = threadIdx.x;
    #pragma unroll
    for (int it = 0; it < 16; ++it) {
        int idx = it * 256 + t;
        int cr = idx >> 6, jc = idx & 63;
        tile[cr][jc] = src[(c0 + cr) * P_DIM + j0 + jc];
    }
    __syncthreads();
    #pragma unroll
    for (int it = 0; it < 16; ++it) {
        int idx = it * 256 + t;
        int jr = idx >> 6, cc = idx & 63;
        dst[(size_t)(j0 + jr) * C_DIM + c0 + cc] = (bf16)(tile[cc][jr] * inv[j0 + jr]);
    }
}

// --- 3. S = Xn * Sn^T with fused per-row running max (no C write) ---
__global__ __launch_bounds__(256, 2) void nnfm_gemm_max(
    const bf16* __restrict__ Xn, const bf16* __restrict__ Sn,
    float* __restrict__ wmax) {
    __shared__ __align__(16) bf16 smA[2][BM * BK];
    __shared__ __align__(16) bf16 smB[2][BN * BK];

    const int bid = blockIdx.x;
    const int iblk = bid >> 2;
    const int split = bid & 3;
    const int i0 = iblk * BM;
    const int jbase = split * (P_DIM / JSPLIT);

    const int tid = threadIdx.x;
    const int lane = tid & 63;
    const int wave = tid >> 6;
    const int wr = (wave >> 1) * 64;
    const int wc = (wave & 1) * 64;

    const int srow_l = wave * 8 + (lane >> 3);   // + it*32 during staging
    const int scol = (lane & 7) * 8;

    f32x4 acc[4][4];
    float rmax[4][4];
    #pragma unroll
    for (int m = 0; m < 4; ++m)
        #pragma unroll
        for (int r = 0; r < 4; ++r) rmax[m][r] = -3.0e38f;

    // prologue: stage first chunk into buf 0
    #pragma unroll
    for (int it = 0; it < 4; ++it) {
        async_copy16(Xn + (size_t)(i0 + it * 32 + srow_l) * C_DIM + scol,
                     &smA[0][(it * 32 + wave * 8) * BK]);
        async_copy16(Sn + (size_t)(jbase + it * 32 + srow_l) * C_DIM + scol,
                     &smB[0][(it * 32 + wave * 8) * BK]);
    }
    __syncthreads();

    int buf = 0;
    const int total = NJT * KCH;
    for (int s = 0; s < total; ++s) {
        const int kk = s - (s / KCH) * KCH;
        const int ns = s + 1;
        if (ns < total) {
            const int njt = ns / KCH;
            const int nkk = ns - njt * KCH;
            const int nk0 = nkk * BK;
            const int nj0 = jbase + njt * BN;
            #pragma unroll
            for (int it = 0; it < 4; ++it) {
                async_copy16(Xn + (size_t)(i0 + it * 32 + srow_l) * C_DIM + nk0 + scol,
                             &smA[buf ^ 1][(it * 32 + wave * 8) * BK]);
                async_copy16(Sn + (size_t)(nj0 + it * 32 + srow_l) * C_DIM + nk0 + scol,
                             &smB[buf ^ 1][(it * 32 + wave * 8) * BK]);
            }
        }
        if (kk == 0) {
            #pragma unroll
            for (int m = 0; m < 4; ++m)
                #pragma unroll
                for (int n = 0; n < 4; ++n)
                    acc[m][n] = f32x4{0.f, 0.f, 0.f, 0.f};
        }
        #pragma unroll
        for (int ks = 0; ks < 2; ++ks) {
            bf16x8 aF[4], bF[4];
            const int koff = ks * 32 + (lane >> 4) * 8;
            #pragma unroll
            for (int m = 0; m < 4; ++m)
                aF[m] = *(const bf16x8*)&smA[buf][(wr + m * 16 + (lane & 15)) * BK + koff];
            #pragma unroll
            for (int n = 0; n < 4; ++n)
                bF[n] = *(const bf16x8*)&smB[buf][(wc + n * 16 + (lane & 15)) * BK + koff];
            #pragma unroll
            for (int m = 0; m < 4; ++m)
                #pragma unroll
                for (int n = 0; n < 4; ++n)
                    acc[m][n] = __builtin_amdgcn_mfma_f32_16x16x32_bf16(aF[m], bF[n], acc[m][n], 0, 0, 0);
        }
        if (kk == KCH - 1) {
            #pragma unroll
            for (int m = 0; m < 4; ++m)
                #pragma unroll
                for (int n = 0; n < 4; ++n)
                    #pragma unroll
                    for (int r = 0; r < 4; ++r)
                        rmax[m][r] = fmaxf(rmax[m][r], acc[m][n][r]);
        }
        __syncthreads();
        buf ^= 1;
    }

    // reduce max across the 16 lanes that share each output row
    #pragma unroll
    for (int m = 0; m < 4; ++m)
        #pragma unroll
        for (int r = 0; r < 4; ++r) {
            float v = rmax[m][r];
            v = fmaxf(v, __shfl_xor(v, 1));
            v = fmaxf(v, __shfl_xor(v, 2));
            v = fmaxf(v, __shfl_xor(v, 4));
            v = fmaxf(v, __shfl_xor(v, 8));
            if ((lane & 15) == 0) {
                const int row = i0 + wr + m * 16 + (lane >> 4) * 4 + r;
                wmax[(size_t)(split * 2 + (wave & 1)) * P_DIM + row] = v;
            }
        }
}

// --- 4. loss = mean(1 - max over 8 partials) ---
__global__ void final_reduce(const float* __restrict__ wmax, float* __restrict__ out) {
    __shared__ float red[256];
    int t = threadIdx.x;
    float sum = 0.f;
    for (int i = t; i < P_DIM; i += 256) {
        float m = wmax[i];
        #pragma unroll
        for (int sp = 1; sp < 8; ++sp) m = fmaxf(m, wmax[(size_t)sp * P_DIM + i]);
        sum += 1.0f - m;
    }
    red[t] = sum;
    __syncthreads();
    for (int st = 128; st > 0; st >>= 1) {
        if (t < st) red[t] += red[t + st];
        __syncthreads();
    }
    if (t == 0) out[0] = red[0] * (1.0f / (float)P_DIM);
}

extern "C" void kernel_launch(void* const* d_in, const int* in_sizes, int n_in,
                              void* d_out, int out_size, void* d_ws, size_t ws_size,
                              hipStream_t stream) {
    const float* x = (const float*)d_in[0];
    const float* s = (const float*)d_in[1];
    float* out = (float*)d_out;
    char* ws = (char*)d_ws;

    bf16* Xn = (bf16*)(ws + OFF_XN);
    bf16* Sn = (bf16*)(ws + OFF_SN);
    float* invx = (float*)(ws + OFF_INVX);
    float* invs = (float*)(ws + OFF_INVS);
    float* wmax = (float*)(ws + OFF_MAX);

    norm_kernel<<<dim3(16, 2), 256, 0, stream>>>(x, s, invx, invs);
    tnorm_kernel<<<dim3(256, 12, 2), 256, 0, stream>>>(x, s, invx, invs, Xn, Sn);
    nnfm_gemm_max<<<dim3(BM == 128 ? (P_DIM / BM) * JSPLIT : 0), 256, 0, stream>>>(Xn, Sn, wmax);
    final_reduce<<<1, 256, 0, stream>>>(wmax, out);
}

// Round 2
// 536.605 us; speedup vs baseline: 1.1753x; 1.1753x over previous
//
#include <hip/hip_runtime.h>
#include <math.h>

// NNFM loss on MI355X.
// loss = mean_i (1 - max_j (xhat_i . shat_j)),  xhat/shat = column-normalized feats.
// Pipeline: norms -> transpose+normalize+bf16 -> MFMA GEMM w/ fused row-max -> reduce.
// R2: XOR-swizzled LDS (pre-swizzled global source + swizzled ds_read) to kill
//     the 1.5e8 16-way bank conflicts of the linear [row][64] layout.

#define C_DIM 768
#define P_DIM 16384
#define BM 128
#define BN 128
#define BK 64
#define KCH 12          // 768/64
#define JSPLIT 4
#define NJT 32          // (P/JSPLIT)/BN
#define EPSF 1e-8f

typedef __bf16 bf16;
typedef bf16 bf16x8 __attribute__((ext_vector_type(8)));
typedef float f32x4 __attribute__((ext_vector_type(4)));

// workspace layout (bytes)
#define OFF_XN   0
#define OFF_SN   25165824UL                 // 16384*768*2
#define OFF_INVX 50331648UL
#define OFF_INVS 50397184UL
#define OFF_MAX  50462720UL                 // 8 * 16384 * 4 = 524288 bytes

__device__ __forceinline__ void async_copy16(const void* gsrc, void* ldst) {
    __builtin_amdgcn_global_load_lds(
        (const __attribute__((address_space(1))) void*)gsrc,
        (__attribute__((address_space(3))) void*)ldst,
        16, 0, 0);
}

// --- 1. column L2 norms (inverse, +eps) for both inputs ---
__global__ void norm_kernel(const float* __restrict__ x, const float* __restrict__ s,
                            float* __restrict__ invx, float* __restrict__ invs) {
    const float4* src = (const float4*)(blockIdx.y == 0 ? x : s);
    float* dst = (blockIdx.y == 0) ? invx : invs;
    int j4 = blockIdx.x * 256 + threadIdx.x;       // 0..4095, each handles 4 columns
    float sx = 0.f, sy = 0.f, sz = 0.f, sw = 0.f;
    for (int c = 0; c < C_DIM; ++c) {
        float4 v = src[c * (P_DIM / 4) + j4];
        sx += v.x * v.x; sy += v.y * v.y; sz += v.z * v.z; sw += v.w * v.w;
    }
    int j = j4 * 4;
    dst[j + 0] = 1.0f / (sqrtf(sx) + EPSF);
    dst[j + 1] = 1.0f / (sqrtf(sy) + EPSF);
    dst[j + 2] = 1.0f / (sqrtf(sz) + EPSF);
    dst[j + 3] = 1.0f / (sqrtf(sw) + EPSF);
}

// --- 2. transpose [c][p] -> [p][c], normalize, cast bf16 ---
__global__ void tnorm_kernel(const float* __restrict__ x, const float* __restrict__ s,
                             const float* __restrict__ invx, const float* __restrict__ invs,
                             bf16* __restrict__ Xn, bf16* __restrict__ Sn) {
    __shared__ float tile[64][65];
    const float* src = blockIdx.z ? s : x;
    const float* inv = blockIdx.z ? invs : invx;
    bf16* dst = blockIdx.z ? Sn : Xn;
    int c0 = blockIdx.y * 64;
    int j0 = blockIdx.x * 64;
    int t = threadIdx.x;
    #pragma unroll
    for (int it = 0; it < 16; ++it) {
        int idx = it * 256 + t;
        int cr = idx >> 6, jc = idx & 63;
        tile[cr][jc] = src[(c0 + cr) * P_DIM + j0 + jc];
    }
    __syncthreads();
    #pragma unroll
    for (int it = 0; it < 16; ++it) {
        int idx = it * 256 + t;
        int jr = idx >> 6, cc = idx & 63;
        dst[(size_t)(j0 + jr) * C_DIM + c0 + cc] = (bf16)(tile[cc][jr] * inv[j0 + jr]);
    }
}

// --- 3. S = Xn * Sn^T with fused per-row running max (no C write) ---
// LDS layout is XOR-swizzled: content(row, cb) = global(row, cb ^ (row&7)),
// cb = 16B column block (0..7). Achieved with a LINEAR LDS dest (global_load_lds
// requirement) by permuting the per-lane GLOBAL source column; since the staged
// row is wave*8 + (lane>>3), row&7 == lane>>3 and the source offset is the
// per-lane constant ((lane&7)^(lane>>3))*8 elements. Reads XOR the same way.
__global__ __launch_bounds__(256, 2) void nnfm_gemm_max(
    const bf16* __restrict__ Xn, const bf16* __restrict__ Sn,
    float* __restrict__ wmax) {
    __shared__ __align__(16) bf16 smA[2][BM * BK];
    __shared__ __align__(16) bf16 smB[2][BN * BK];

    const int bid = blockIdx.x;
    const int iblk = bid >> 2;
    const int split = bid & 3;
    const int i0 = iblk * BM;
    const int jbase = split * (P_DIM / JSPLIT);

    const int tid = threadIdx.x;
    const int lane = tid & 63;
    const int wave = tid >> 6;
    const int wr = (wave >> 1) * 64;
    const int wc = (wave & 1) * 64;

    const int srow_l = wave * 8 + (lane >> 3);             // + it*32 during staging
    const int scol = (((lane & 7) ^ (lane >> 3)) * 8);     // swizzled source column

    // swizzled read column (elements) for each ks: ((ks*4 + lane>>4) ^ (lane&7)) * 8
    const int kidx0 = (((lane >> 4) + 0) ^ (lane & 7)) * 8;
    const int kidx1 = (((lane >> 4) + 4) ^ (lane & 7)) * 8;

    f32x4 acc[4][4];
    float rmax[4][4];
    #pragma unroll
    for (int m = 0; m < 4; ++m)
        #pragma unroll
        for (int r = 0; r < 4; ++r) rmax[m][r] = -3.0e38f;

    // prologue: stage first chunk into buf 0
    #pragma unroll
    for (int it = 0; it < 4; ++it) {
        async_copy16(Xn + (size_t)(i0 + it * 32 + srow_l) * C_DIM + scol,
                     &smA[0][(it * 32 + wave * 8) * BK]);
        async_copy16(Sn + (size_t)(jbase + it * 32 + srow_l) * C_DIM + scol,
                     &smB[0][(it * 32 + wave * 8) * BK]);
    }
    __syncthreads();

    int buf = 0;
    const int total = NJT * KCH;
    for (int s = 0; s < total; ++s) {
        const int kk = s - (s / KCH) * KCH;
        const int ns = s + 1;
        if (ns < total) {
            const int njt = ns / KCH;
            const int nkk = ns - njt * KCH;
            const int nk0 = nkk * BK;
            const int nj0 = jbase + njt * BN;
            #pragma unroll
            for (int it = 0; it < 4; ++it) {
                async_copy16(Xn + (size_t)(i0 + it * 32 + srow_l) * C_DIM + nk0 + scol,
                             &smA[buf ^ 1][(it * 32 + wave * 8) * BK]);
                async_copy16(Sn + (size_t)(nj0 + it * 32 + srow_l) * C_DIM + nk0 + scol,
                             &smB[buf ^ 1][(it * 32 + wave * 8) * BK]);
            }
        }
        if (kk == 0) {
            #pragma unroll
            for (int m = 0; m < 4; ++m)
                #pragma unroll
                for (int n = 0; n < 4; ++n)
                    acc[m][n] = f32x4{0.f, 0.f, 0.f, 0.f};
        }
        #pragma unroll
        for (int ks = 0; ks < 2; ++ks) {
            bf16x8 aF[4], bF[4];
            const int kidx = ks ? kidx1 : kidx0;
            #pragma unroll
            for (int m = 0; m < 4; ++m)
                aF[m] = *(const bf16x8*)&smA[buf][(wr + m * 16 + (lane & 15)) * BK + kidx];
            #pragma unroll
            for (int n = 0; n < 4; ++n)
                bF[n] = *(const bf16x8*)&smB[buf][(wc + n * 16 + (lane & 15)) * BK + kidx];
            #pragma unroll
            for (int m = 0; m < 4; ++m)
                #pragma unroll
                for (int n = 0; n < 4; ++n)
                    acc[m][n] = __builtin_amdgcn_mfma_f32_16x16x32_bf16(aF[m], bF[n], acc[m][n], 0, 0, 0);
        }
        if (kk == KCH - 1) {
            #pragma unroll
            for (int m = 0; m < 4; ++m)
                #pragma unroll
                for (int n = 0; n < 4; ++n)
                    #pragma unroll
                    for (int r = 0; r < 4; ++r)
                        rmax[m][r] = fmaxf(rmax[m][r], acc[m][n][r]);
        }
        __syncthreads();
        buf ^= 1;
    }

    // reduce max across the 16 lanes that share each output row
    #pragma unroll
    for (int m = 0; m < 4; ++m)
        #pragma unroll
        for (int r = 0; r < 4; ++r) {
            float v = rmax[m][r];
            v = fmaxf(v, __shfl_xor(v, 1));
            v = fmaxf(v, __shfl_xor(v, 2));
            v = fmaxf(v, __shfl_xor(v, 4));
            v = fmaxf(v, __shfl_xor(v, 8));
            if ((lane & 15) == 0) {
                const int row = i0 + wr + m * 16 + (lane >> 4) * 4 + r;
                wmax[(size_t)(split * 2 + (wave & 1)) * P_DIM + row] = v;
            }
        }
}

// --- 4. loss = mean(1 - max over 8 partials) ---
__global__ void final_reduce(const float* __restrict__ wmax, float* __restrict__ out) {
    __shared__ float red[256];
    int t = threadIdx.x;
    float sum = 0.f;
    for (int i = t; i < P_DIM; i += 256) {
        float m = wmax[i];
        #pragma unroll
        for (int sp = 1; sp < 8; ++sp) m = fmaxf(m, wmax[(size_t)sp * P_DIM + i]);
        sum += 1.0f - m;
    }
    red[t] = sum;
    __syncthreads();
    for (int st = 128; st > 0; st >>= 1) {
        if (t < st) red[t] += red[t + st];
        __syncthreads();
    }
    if (t == 0) out[0] = red[0] * (1.0f / (float)P_DIM);
}

extern "C" void kernel_launch(void* const* d_in, const int* in_sizes, int n_in,
                              void* d_out, int out_size, void* d_ws, size_t ws_size,
                              hipStream_t stream) {
    const float* x = (const float*)d_in[0];
    const float* s = (const float*)d_in[1];
    float* out = (float*)d_out;
    char* ws = (char*)d_ws;

    bf16* Xn = (bf16*)(ws + OFF_XN);
    bf16* Sn = (bf16*)(ws + OFF_SN);
    float* invx = (float*)(ws + OFF_INVX);
    float* invs = (float*)(ws + OFF_INVS);
    float* wmax = (float*)(ws + OFF_MAX);

    norm_kernel<<<dim3(16, 2), 256, 0, stream>>>(x, s, invx, invs);
    tnorm_kernel<<<dim3(256, 12, 2), 256, 0, stream>>>(x, s, invx, invs, Xn, Sn);
    nnfm_gemm_max<<<dim3((P_DIM / BM) * JSPLIT), 256, 0, stream>>>(Xn, Sn, wmax);
    final_reduce<<<1, 256, 0, stream>>>(wmax, out);
}

// Round 3
// 495.476 us; speedup vs baseline: 1.2728x; 1.0830x over previous
//
#include <hip/hip_runtime.h>
#include <math.h>

// NNFM loss on MI355X.
// loss = mean_i (1 - max_j (xhat_i . shat_j)),  xhat/shat = column-normalized feats.
// Pipeline: norms -> transpose+normalize+bf16 -> MFMA GEMM w/ fused row-max -> reduce.
// R2: XOR-swizzled LDS -> bank conflicts 1.5e8 -> 0, 475us (m97 ceiling).
// R3: 256^2-tile 8-wave 4-phase-per-K-tile schedule (T3+T4+T5): raw s_barrier,
//     counted vmcnt(2) once per K-tile (never drain-0 in loop), setprio around MFMA.

#define C_DIM 768
#define P_DIM 16384
#define KT 12           // K-tiles (BK=64) per j-tile: 768/64
#define NJT 16          // j-tiles per block: (P/JSPLIT)/256
#define JSPLIT 4
#define EPSF 1e-8f

typedef __bf16 bf16;
typedef bf16 bf16x8 __attribute__((ext_vector_type(8)));
typedef float f32x4 __attribute__((ext_vector_type(4)));

// workspace layout (bytes); high-water 50724864 < R2-proven 50987008
#define OFF_XN   0
#define OFF_SN   25165824UL                 // 16384*768*2
#define OFF_INVX 50331648UL
#define OFF_INVS 50397184UL
#define OFF_MAX  50462720UL                 // 4 * 16384 * 4 = 262144 bytes

__device__ __forceinline__ void async_copy16(const void* gsrc, void* ldst) {
    __builtin_amdgcn_global_load_lds(
        (const __attribute__((address_space(1))) void*)gsrc,
        (__attribute__((address_space(3))) void*)ldst,
        16, 0, 0);
}

#define CFENCE() asm volatile("" ::: "memory")
#define BARRIER() { CFENCE(); __builtin_amdgcn_s_barrier(); CFENCE(); }

// --- 1. column L2 norms (inverse, +eps) for both inputs ---
__global__ void norm_kernel(const float* __restrict__ x, const float* __restrict__ s,
                            float* __restrict__ invx, float* __restrict__ invs) {
    const float4* src = (const float4*)(blockIdx.y == 0 ? x : s);
    float* dst = (blockIdx.y == 0) ? invx : invs;
    int j4 = blockIdx.x * 256 + threadIdx.x;
    float sx = 0.f, sy = 0.f, sz = 0.f, sw = 0.f;
    for (int c = 0; c < C_DIM; ++c) {
        float4 v = src[c * (P_DIM / 4) + j4];
        sx += v.x * v.x; sy += v.y * v.y; sz += v.z * v.z; sw += v.w * v.w;
    }
    int j = j4 * 4;
    dst[j + 0] = 1.0f / (sqrtf(sx) + EPSF);
    dst[j + 1] = 1.0f / (sqrtf(sy) + EPSF);
    dst[j + 2] = 1.0f / (sqrtf(sz) + EPSF);
    dst[j + 3] = 1.0f / (sqrtf(sw) + EPSF);
}

// --- 2. transpose [c][p] -> [p][c], normalize, cast bf16 ---
__global__ void tnorm_kernel(const float* __restrict__ x, const float* __restrict__ s,
                             const float* __restrict__ invx, const float* __restrict__ invs,
                             bf16* __restrict__ Xn, bf16* __restrict__ Sn) {
    __shared__ float tile[64][65];
    const float* src = blockIdx.z ? s : x;
    const float* inv = blockIdx.z ? invs : invx;
    bf16* dst = blockIdx.z ? Sn : Xn;
    int c0 = blockIdx.y * 64;
    int j0 = blockIdx.x * 64;
    int t = threadIdx.x;
    #pragma unroll
    for (int it = 0; it < 16; ++it) {
        int idx = it * 256 + t;
        int cr = idx >> 6, jc = idx & 63;
        tile[cr][jc] = src[(c0 + cr) * P_DIM + j0 + jc];
    }
    __syncthreads();
    #pragma unroll
    for (int it = 0; it < 16; ++it) {
        int idx = it * 256 + t;
        int jr = idx >> 6, cc = idx & 63;
        dst[(size_t)(j0 + jr) * C_DIM + c0 + cc] = (bf16)(tile[cc][jr] * inv[j0 + jr]);
    }
}

// --- 3. 256x256-tile GEMM with fused per-row running max ---
// 8 waves (2M x 4N); per-wave output 128x64; 4 phases per K-tile (BK=64):
//   quadrants (mh,nh) = (0,0),(0,1),(1,1),(1,0)
// Staging schedule (1 half-tile = 2 global_load_lds per phase), derived slot
// lifetimes: A-half of K-tile h dead after phase 2 of h; B-half dead after ph 3.
//   p0: A(h+1)hi  p1: B(h+1)lo  p2: B(h+1)hi  p3: A(h+2)lo
// Boundary sync: 10 loads outstanding, oldest 8 = all of K-tile h+1 -> vmcnt(2).
__global__ __launch_bounds__(512, 2) void nnfm_gemm_max(
    const bf16* __restrict__ Xn, const bf16* __restrict__ Sn,
    float* __restrict__ wmax) {
    __shared__ __align__(16) bf16 smA[2][256 * 64];
    __shared__ __align__(16) bf16 smB[2][256 * 64];

    const int bid = blockIdx.x;
    const int iblk = bid >> 2;
    const int split = bid & 3;
    const int i0 = iblk * 256;
    const int jbase = split * (P_DIM / JSPLIT);

    const int tid = threadIdx.x;
    const int lane = tid & 63;
    const int wid = tid >> 6;
    const int wr = (wid >> 2) * 128;
    const int wc = (wid & 3) * 64;
    const int lm = lane & 15;

    const int srow = wid * 8 + (lane >> 3);
    const int scol = ((lane & 7) ^ (lane >> 3)) * 8;
    const int koff0 = (((lane >> 4) + 0) ^ (lane & 7)) * 8;
    const int koff1 = (((lane >> 4) + 4) ^ (lane & 7)) * 8;
    const int rA = (wr + lm) * 64;
    const int rB = (wc + lm) * 64;

#define STAGE_A(kk_t, buf_t, half) { \
    _Pragma("unroll") \
    for (int ld = 0; ld < 2; ++ld) \
      async_copy16(Xn + (size_t)(i0 + (half) * 128 + ld * 64 + srow) * C_DIM + (kk_t) * 64 + scol, \
                   &smA[buf_t][((half) * 128 + ld * 64 + wid * 8) * 64]); }

#define STAGE_B(jt_t, kk_t, buf_t, half) { \
    _Pragma("unroll") \
    for (int ld = 0; ld < 2; ++ld) \
      async_copy16(Sn + (size_t)(jbase + (jt_t) * 256 + (half) * 128 + ld * 64 + srow) * C_DIM + (kk_t) * 64 + scol, \
                   &smB[buf_t][((half) * 128 + ld * 64 + wid * 8) * 64]); }

#define READ_A(MH) { \
    _Pragma("unroll") \
    for (int m = 0; m < 4; ++m) { \
      aF[m][0] = *(const bf16x8*)&Ab[((MH) * 64 + m * 16) * 64 + rA + koff0]; \
      aF[m][1] = *(const bf16x8*)&Ab[((MH) * 64 + m * 16) * 64 + rA + koff1]; \
    } }

#define READ_B(NH) { \
    _Pragma("unroll") \
    for (int n = 0; n < 2; ++n) { \
      bF[n][0] = *(const bf16x8*)&Bb[((NH) * 32 + n * 16) * 64 + rB + koff0]; \
      bF[n][1] = *(const bf16x8*)&Bb[((NH) * 32 + n * 16) * 64 + rB + koff1]; \
    } }

#define ZERO_QUAD(MH, NH) { \
    _Pragma("unroll") \
    for (int m = 0; m < 4; ++m) \
      _Pragma("unroll") \
      for (int n = 0; n < 2; ++n) \
        acc[(MH) * 4 + m][(NH) * 2 + n] = f32x4{0.f, 0.f, 0.f, 0.f}; }

#define MFMA_QUAD(MH, NH) { \
    __builtin_amdgcn_s_setprio(1); \
    _Pragma("unroll") \
    for (int ks = 0; ks < 2; ++ks) \
      _Pragma("unroll") \
      for (int m = 0; m < 4; ++m) \
        _Pragma("unroll") \
        for (int n = 0; n < 2; ++n) \
          acc[(MH) * 4 + m][(NH) * 2 + n] = __builtin_amdgcn_mfma_f32_16x16x32_bf16( \
              aF[m][ks], bF[n][ks], acc[(MH) * 4 + m][(NH) * 2 + n], 0, 0, 0); \
    __builtin_amdgcn_s_setprio(0); }

#define RMAX_QUAD(MH, NH) { \
    _Pragma("unroll") \
    for (int m = 0; m < 4; ++m) \
      _Pragma("unroll") \
      for (int r = 0; r < 4; ++r) \
        rmax[(MH) * 4 + m][r] = fmaxf(rmax[(MH) * 4 + m][r], \
            fmaxf(acc[(MH) * 4 + m][(NH) * 2 + 0][r], acc[(MH) * 4 + m][(NH) * 2 + 1][r])); }

    f32x4 acc[8][4];
    float rmax[8][4];
    bf16x8 aF[4][2], bF[2][2];
    #pragma unroll
    for (int m = 0; m < 8; ++m)
        #pragma unroll
        for (int r = 0; r < 4; ++r) rmax[m][r] = -3.0e38f;

    // prologue: K-tile 0 complete + A1lo (10 loads); first 8 must land -> vmcnt(2)
    STAGE_A(0, 0, 0); STAGE_A(0, 0, 1);
    STAGE_B(0, 0, 0, 0); STAGE_B(0, 0, 0, 1);
    STAGE_A(1, 1, 0);
    asm volatile("s_waitcnt vmcnt(2)" ::: "memory");
    BARRIER();

    for (int jt = 0; jt < NJT; ++jt) {
        for (int kk = 0; kk < KT; ++kk) {
            const int buf = kk & 1;
            int kk1 = kk + 1, jt1 = jt;
            if (kk1 == KT) { kk1 = 0; jt1 = (jt + 1) & (NJT - 1); }
            int kk2 = kk + 2, jt2 = jt;
            if (kk2 >= KT) { kk2 -= KT; jt2 = (jt + 1) & (NJT - 1); }
            const bf16* Ab = &smA[buf][0];
            const bf16* Bb = &smB[buf][0];

            // ---- phase 0: quadrant (0,0) ----
            READ_A(0) READ_B(0)
            STAGE_A(kk1, buf ^ 1, 1);
            BARRIER();
            if (kk == 0) ZERO_QUAD(0, 0)
            MFMA_QUAD(0, 0)
            if (kk == KT - 1) RMAX_QUAD(0, 0)
            BARRIER();

            // ---- phase 1: quadrant (0,1) ----
            READ_B(1)
            STAGE_B(jt1, kk1, buf ^ 1, 0);
            BARRIER();
            if (kk == 0) ZERO_QUAD(0, 1)
            MFMA_QUAD(0, 1)
            if (kk == KT - 1) RMAX_QUAD(0, 1)
            BARRIER();

            // ---- phase 2: quadrant (1,1) ----
            READ_A(1)
            STAGE_B(jt1, kk1, buf ^ 1, 1);
            BARRIER();
            if (kk == 0) ZERO_QUAD(1, 1)
            MFMA_QUAD(1, 1)
            if (kk == KT - 1) RMAX_QUAD(1, 1)
            BARRIER();

            // ---- phase 3: quadrant (1,0) ----
            READ_B(0)
            STAGE_A(kk2, buf, 0);
            BARRIER();
            if (kk == 0) ZERO_QUAD(1, 0)
            MFMA_QUAD(1, 0)
            if (kk == KT - 1) RMAX_QUAD(1, 0)
            asm volatile("s_waitcnt vmcnt(2)" ::: "memory");
            BARRIER();
        }
    }

    // epilogue: drain all in-flight LDS DMA before reusing LDS for reduction
    asm volatile("s_waitcnt vmcnt(0)" ::: "memory");
    BARRIER();

    float* red = (float*)&smA[0][0];   // [4 col-waves][256 rows]
    #pragma unroll
    for (int m8 = 0; m8 < 8; ++m8)
        #pragma unroll
        for (int r = 0; r < 4; ++r) {
            float v = rmax[m8][r];
            v = fmaxf(v, __shfl_xor(v, 1));
            v = fmaxf(v, __shfl_xor(v, 2));
            v = fmaxf(v, __shfl_xor(v, 4));
            v = fmaxf(v, __shfl_xor(v, 8));
            if (lm == 0) {
                const int row_l = wr + (m8 >> 2) * 64 + (m8 & 3) * 16 + (lane >> 4) * 4 + r;
                red[(wid & 3) * 256 + row_l] = v;
            }
        }
    BARRIER();
    if (tid < 256) {
        float v = fmaxf(fmaxf(red[tid], red[256 + tid]),
                        fmaxf(red[512 + tid], red[768 + tid]));
        wmax[(size_t)split * P_DIM + i0 + tid] = v;
    }
}

// --- 4. loss = mean(1 - max over 4 partials) ---
__global__ void final_reduce(const float* __restrict__ wmax, float* __restrict__ out) {
    __shared__ float red[256];
    int t = threadIdx.x;
    float sum = 0.f;
    for (int i = t; i < P_DIM; i += 256) {
        float m = wmax[i];
        #pragma unroll
        for (int sp = 1; sp < 4; ++sp) m = fmaxf(m, wmax[(size_t)sp * P_DIM + i]);
        sum += 1.0f - m;
    }
    red[t] = sum;
    __syncthreads();
    for (int st = 128; st > 0; st >>= 1) {
        if (t < st) red[t] += red[t + st];
        __syncthreads();
    }
    if (t == 0) out[0] = red[0] * (1.0f / (float)P_DIM);
}

extern "C" void kernel_launch(void* const* d_in, const int* in_sizes, int n_in,
                              void* d_out, int out_size, void* d_ws, size_t ws_size,
                              hipStream_t stream) {
    const float* x = (const float*)d_in[0];
    const float* s = (const float*)d_in[1];
    float* out = (float*)d_out;
    char* ws = (char*)d_ws;

    bf16* Xn = (bf16*)(ws + OFF_XN);
    bf16* Sn = (bf16*)(ws + OFF_SN);
    float* invx = (float*)(ws + OFF_INVX);
    float* invs = (float*)(ws + OFF_INVS);
    float* wmax = (float*)(ws + OFF_MAX);

    norm_kernel<<<dim3(16, 2), 256, 0, stream>>>(x, s, invx, invs);
    tnorm_kernel<<<dim3(256, 12, 2), 256, 0, stream>>>(x, s, invx, invs, Xn, Sn);
    nnfm_gemm_max<<<dim3((P_DIM / 256) * JSPLIT), 512, 0, stream>>>(Xn, Sn, wmax);
    final_reduce<<<1, 256, 0, stream>>>(wmax, out);
}